// Round 6
// baseline (160.555 us; speedup 1.0000x reference)
//
#include <hip/hip_runtime.h>

#define ALPHA 0.2f

__device__ __forceinline__ float dot4(float4 a, float4 b) {
    return a.x * b.x + a.y * b.y + a.z * b.z + a.w * b.w;
}

__device__ __forceinline__ void lds_fence() {
    asm volatile("s_waitcnt lgkmcnt(0)" ::: "memory");
    __builtin_amdgcn_sched_barrier(0);
}

// async HBM -> LDS, 16B/lane, zero VGPR. LDS dest: wave-uniform base + 16*lane.
__device__ __forceinline__ void async16(const float* g, float* l) {
    __builtin_amdgcn_global_load_lds(
        (const __attribute__((address_space(1))) void*)g,
        (__attribute__((address_space(3))) void*)l, 16, 0, 0);
}

#define VMW(imm) do { \
    asm volatile("s_waitcnt vmcnt(" imm ")" ::: "memory"); \
    __builtin_amdgcn_sched_barrier(0); } while (0)

// e-pass chunk from staged LDS (uses sp, l, fr, fe, ep from enclosing scope)
#define ECH(c, imm) \
    VMW(imm); \
    { float4 rv = *(const float4*)(sp + (c) * 512 + 4 * l); \
      float4 ev = *(const float4*)(sp + (c) * 512 + 256 + 4 * l); \
      ep[c] = dot4(rv, fr) + dot4(ev, fe); }

// One node iteration: consume node NCUR from buf SPOFF + reg set Rc/Sc;
// prefetch node NCUR+GS into buf SQOFF + reg set Rn/Sn.
#define ITER(NCUR, SPOFF, SQOFF, RcR, RcE, RnR, RnE, ScIT, ScADJ, ScID, SnIT, SnADJ, SnID) do { \
    const float* sp = &slab[SPOFF]; \
    float ep[16]; \
    ECH(0, "31")  ECH(1, "29")  ECH(2, "27")  ECH(3, "25") \
    ECH(4, "23")  ECH(5, "21")  ECH(6, "19")  ECH(7, "17") \
    ECH(8, "15")  ECH(9, "13")  ECH(10, "11") ECH(11, "9") \
    _Pragma("unroll") \
    for (int c = 0; c < 4; ++c) \
        ep[12 + c] = dot4(RcR[c], fr) + dot4(RcE[c], fe); \
    { /* ---- prefetch issue for node np (clamped; clamp never consumed) */ \
      int np = (NCUR) + GS; if (np >= N) np = n0; \
      const float* bR = rel + (size_t)np * 4096 + 4 * l; \
      const float* bE = ent + (size_t)np * 4096 + 4 * l; \
      float* sq = &slab[SQOFF]; \
      lds_fence(); \
      _Pragma("unroll") \
      for (int c = 0; c < 12; ++c) { \
          async16(bR + c * 256, sq + c * 512); \
          async16(bE + c * 256, sq + c * 512 + 256); } \
      __builtin_amdgcn_sched_barrier(0); /* keep reg/small loads BELOW asyncs */ \
      _Pragma("unroll") \
      for (int c = 0; c < 4; ++c) { \
          RnR[c] = *(const float4*)(bR + (12 + c) * 256); \
          RnE[c] = *(const float4*)(bE + (12 + c) * 256); } \
      SnIT  = *(const float4*)&item[(size_t)np * 128 + 4 * lh]; \
      SnADJ = adj[(size_t)np * 32 + lh]; \
      SnID  = rel_ids[(size_t)np * 32 + lh]; \
    } \
    /* ---- reduce e within each 32-lane half ---- */ \
    float sit = dot4(ScIT, fi); \
    _Pragma("unroll") \
    for (int s = 16; s >= 1; s >>= 1) sit += __shfl_xor(sit, s, 32); \
    _Pragma("unroll") \
    for (int c = 0; c < 16; ++c) { \
        float v = ep[c]; \
        _Pragma("unroll") \
        for (int s = 16; s >= 1; s >>= 1) v += __shfl_xor(v, s, 32); \
        ep[c] = v; } \
    if (lh == 0) { \
        _Pragma("unroll") \
        for (int c = 0; c < 16; ++c) strip[2 * c + hi] = ep[c]; } \
    lds_fence(); \
    /* ---- masked softmax (no max-sub; N(0,1) inputs, fp32-safe) ---- */ \
    float e = strip[lh] + sit + fcb; \
    e = (e > 0.0f) ? e : ALPHA * e; \
    float ex = (ScADJ > 0) ? __expf(e) : 0.0f; \
    float Z = ex; \
    _Pragma("unroll") \
    for (int s = 16; s >= 1; s >>= 1) Z += __shfl_xor(Z, s, 32); \
    const bool vld = (ScID >= 0) && (ScID < R); \
    const float av = vld ? asum[ScID] : 0.0f; \
    const float wk = (Z > 0.0f) ? (ex * av / Z) : (av * (1.0f / 32.0f)); \
    /* ---- aggregate (n+1 stream in flight), merge halves, store ---- */ \
    float4 acc = make_float4(0.f, 0.f, 0.f, 0.f); \
    _Pragma("unroll") \
    for (int c = 0; c < 12; ++c) { \
        const float wc = __shfl(wk, 2 * c + hi, 64); \
        float4 rv = *(const float4*)(sp + c * 512 + 4 * l); \
        float4 ev = *(const float4*)(sp + c * 512 + 256 + 4 * l); \
        acc.x = fmaf(wc, rv.x * ev.x, acc.x); \
        acc.y = fmaf(wc, rv.y * ev.y, acc.y); \
        acc.z = fmaf(wc, rv.z * ev.z, acc.z); \
        acc.w = fmaf(wc, rv.w * ev.w, acc.w); } \
    _Pragma("unroll") \
    for (int c = 0; c < 4; ++c) { \
        const float wc = __shfl(wk, 2 * (12 + c) + hi, 64); \
        acc.x = fmaf(wc, RcR[c].x * RcE[c].x, acc.x); \
        acc.y = fmaf(wc, RcR[c].y * RcE[c].y, acc.y); \
        acc.z = fmaf(wc, RcR[c].z * RcE[c].z, acc.z); \
        acc.w = fmaf(wc, RcR[c].w * RcE[c].w, acc.w); } \
    acc.x += __shfl_xor(acc.x, 32, 64); \
    acc.y += __shfl_xor(acc.y, 32, 64); \
    acc.z += __shfl_xor(acc.z, 32, 64); \
    acc.w += __shfl_xor(acc.w, 32, 64); \
    if (l < 32) { \
        float4 o; \
        o.x = acc.x + ScIT.x; o.y = acc.y + ScIT.y; \
        o.z = acc.z + ScIT.z; o.w = acc.w + ScIT.w; \
        *(float4*)&y[(size_t)(NCUR) * 128 + 4 * lh] = o; } \
} while (0)

// K1: one wave/block, double-buffered async staging, depth-1 node pipeline.
__global__ __launch_bounds__(64, 1)
void gat_k1(const float* __restrict__ item,
            const float* __restrict__ ent,
            const float* __restrict__ rel,
            const int*   __restrict__ rel_ids,
            const int*   __restrict__ adj,
            const float* __restrict__ fc_w,
            const float* __restrict__ fc_b,
            const float* __restrict__ probs,
            float* __restrict__ y,
            int N, int R)
{
    __shared__ __align__(16) float slab[12288];  // 2 bufs x 12 pairs x 512 f = 48KB
    __shared__ float strip[32];
    __shared__ float asum[128];

    const int l  = threadIdx.x;
    const int lh = l & 31;
    const int hi = l >> 5;

    for (int i = l; i < R; i += 64) {
        float4 q = *(const float4*)&probs[i * 4];
        asum[i] = q.x + q.y + q.z + q.w;
    }
    const float4 fi = *(const float4*)&fc_w[4 * lh];
    const float4 fr = *(const float4*)&fc_w[128 + 4 * lh];
    const float4 fe = *(const float4*)&fc_w[256 + 4 * lh];
    const float fcb = fc_b[0];
    lds_fence();

    const int GS = gridDim.x;
    const int n0 = blockIdx.x;

    float4 rA[4], eA[4], rB[4], eB[4];
    float4 itA, itB;
    int adjA = 0, idA = 0, adjB = 0, idB = 0;

    // prologue: full issue for node n0 -> buf0 + set A (queue: 24 async + 8 reg + 3 small)
    {
        const float* bR = rel + (size_t)n0 * 4096 + 4 * l;
        const float* bE = ent + (size_t)n0 * 4096 + 4 * l;
        #pragma unroll
        for (int c = 0; c < 12; ++c) {
            async16(bR + c * 256, &slab[c * 512]);
            async16(bE + c * 256, &slab[c * 512 + 256]);
        }
        __builtin_amdgcn_sched_barrier(0);
        #pragma unroll
        for (int c = 0; c < 4; ++c) {
            rA[c] = *(const float4*)(bR + (12 + c) * 256);
            eA[c] = *(const float4*)(bE + (12 + c) * 256);
        }
        itA  = *(const float4*)&item[(size_t)n0 * 128 + 4 * lh];
        adjA = adj[(size_t)n0 * 32 + lh];
        idA  = rel_ids[(size_t)n0 * 32 + lh];
    }

    int n = n0;
    while (true) {
        ITER(n, 0, 6144, rA, eA, rB, eB, itA, adjA, idA, itB, adjB, idB);
        n += GS; if (n >= N) break;
        ITER(n, 6144, 0, rB, eB, rA, eA, itB, adjB, idB, itA, adjA, idA);
        n += GS; if (n >= N) break;
    }
}

// K2: out = relu(y @ W^T + b), in place on d_out (unchanged).
__device__ __forceinline__ void block_bar() {
    asm volatile("s_waitcnt lgkmcnt(0)" ::: "memory");
    __builtin_amdgcn_s_barrier();
}

__global__ __launch_bounds__(256, 4)
void gat_k2(const float* __restrict__ out_w,
            const float* __restrict__ out_b,
            float* __restrict__ y, int N)
{
    __shared__ __align__(16) float ylds[128];
    __shared__ __align__(16) float plds[1024];   // [4 a][32 g][8 c]

    const int t = threadIdx.x;
    const int c = t & 7;
    const int g = t >> 3;

    float4 w4[16];
    #pragma unroll
    for (int a = 0; a < 4; ++a)
        #pragma unroll
        for (int i = 0; i < 4; ++i)
            w4[a * 4 + i] = *(const float4*)&out_w[(size_t)(g * 4 + a) * 128 + c * 16 + i * 4];
    const float bj = out_b[t & 127];
    const int stride = gridDim.x;

    float vcur = 0.0f;
    if (t < 128) vcur = y[(size_t)blockIdx.x * 128 + t];

    for (int n = blockIdx.x; n < N; n += stride) {
        if (t < 128) ylds[t] = vcur;
        block_bar();
        int np = n + stride; if (np >= N) np = n;
        float vn = 0.0f;
        if (t < 128) vn = y[(size_t)np * 128 + t];

        float4 yc[4];
        #pragma unroll
        for (int i = 0; i < 4; ++i) yc[i] = *(const float4*)&ylds[c * 16 + i * 4];
        #pragma unroll
        for (int a = 0; a < 4; ++a) {
            float s = 0.0f;
            #pragma unroll
            for (int i = 0; i < 4; ++i) s += dot4(w4[a * 4 + i], yc[i]);
            plds[a * 256 + g * 8 + c] = s;
        }
        block_bar();
        if (t < 128) {
            const int j = t, a2 = j & 3, g2 = j >> 2;
            const float* pp = &plds[a2 * 256 + g2 * 8];
            float4 u0 = *(const float4*)pp;
            float4 u1 = *(const float4*)(pp + 4);
            float s = u0.x + u0.y + u0.z + u0.w + u1.x + u1.y + u1.z + u1.w + bj;
            y[(size_t)n * 128 + j] = fmaxf(s, 0.0f);
        }
        vcur = vn;
    }
}

extern "C" void kernel_launch(void* const* d_in, const int* in_sizes, int n_in,
                              void* d_out, int out_size, void* d_ws, size_t ws_size,
                              hipStream_t stream) {
    const float* item    = (const float*)d_in[0];
    const float* ent     = (const float*)d_in[1];
    const float* rel     = (const float*)d_in[2];
    const int*   rel_ids = (const int*)  d_in[3];
    const int*   adj     = (const int*)  d_in[4];
    const float* fc_w    = (const float*)d_in[5];
    const float* fc_b    = (const float*)d_in[6];
    const float* out_w   = (const float*)d_in[7];
    const float* out_b   = (const float*)d_in[8];
    const float* probs   = (const float*)d_in[9];
    float* out = (float*)d_out;

    const int N = in_sizes[0] / 128;   // 20000
    const int R = in_sizes[9] / 4;     // 100

    // 768 single-wave persistent blocks = 3 blocks/CU (LDS 48.6KB each).
    hipLaunchKernelGGL(gat_k1, dim3(768), dim3(64), 0, stream,
                       item, ent, rel, rel_ids, adj, fc_w, fc_b, probs, out, N, R);

    int blocks2 = 2048; if (blocks2 > N) blocks2 = N;
    hipLaunchKernelGGL(gat_k2, dim3(blocks2), dim3(256), 0, stream,
                       out_w, out_b, out, N);
}

// Round 7
// 159.762 us; speedup vs baseline: 1.0050x; 1.0050x over previous
//
#include <hip/hip_runtime.h>

#define ALPHA 0.2f

__device__ __forceinline__ float dot4(float4 a, float4 b) {
    return a.x * b.x + a.y * b.y + a.z * b.z + a.w * b.w;
}

__device__ __forceinline__ void block_bar() {
    // drain LDS ops only; global prefetch loads stay in flight
    asm volatile("s_waitcnt lgkmcnt(0)" ::: "memory");
    __builtin_amdgcn_s_barrier();
}

// K1: 4 waves cooperate on one node (8 k's each). No LDS slab; P in registers.
// High occupancy (16 waves/CU) with every wave streaming plain float4 loads.
__global__ __launch_bounds__(256, 4)
void gat_k1(const float* __restrict__ item,
            const float* __restrict__ ent,
            const float* __restrict__ rel,
            const int*   __restrict__ rel_ids,
            const int*   __restrict__ adj,
            const float* __restrict__ fc_w,
            const float* __restrict__ fc_b,
            const float* __restrict__ probs,
            float* __restrict__ y,
            int N, int R)
{
    __shared__ float e_lds[32];
    __shared__ __align__(16) float part[4][128];
    __shared__ float asum[128];

    const int t  = threadIdx.x;
    const int w  = t >> 6;       // wave 0..3
    const int l  = t & 63;
    const int lh = l & 31;       // d-quad index (data) and k index (softmax)
    const int hi = l >> 5;
    const int kb = w * 8;        // this wave's k-range [kb, kb+8)

    for (int i = t; i < R; i += 256) {
        float4 q = *(const float4*)&probs[i * 4];
        asum[i] = q.x + q.y + q.z + q.w;
    }
    const float4 fi = *(const float4*)&fc_w[4 * lh];
    const float4 fr = *(const float4*)&fc_w[128 + 4 * lh];
    const float4 fe = *(const float4*)&fc_w[256 + 4 * lh];
    const float fcb = fc_b[0];
    __syncthreads();

    const int ST = gridDim.x;
    const int n0 = blockIdx.x;

    // prologue: load node n0 into current registers
    float4 rc[4], ec[4], itc;
    int adjc, idc;
    {
        const float* bR = rel + (size_t)n0 * 4096;
        const float* bE = ent + (size_t)n0 * 4096;
        #pragma unroll
        for (int c = 0; c < 4; ++c) {
            const int kk = kb + 2 * c + hi;
            rc[c] = *(const float4*)&bR[kk * 128 + 4 * lh];
            ec[c] = *(const float4*)&bE[kk * 128 + 4 * lh];
        }
        itc  = *(const float4*)&item[(size_t)n0 * 128 + 4 * lh];
        adjc = adj[(size_t)n0 * 32 + lh];
        idc  = rel_ids[(size_t)n0 * 32 + lh];
    }

    for (int n = n0; n < N; n += ST) {
        // ---- consume current regs: products + e-partials ------------------
        float4 p[4];
        float  ep[4];
        #pragma unroll
        for (int c = 0; c < 4; ++c) {
            p[c].x = rc[c].x * ec[c].x;
            p[c].y = rc[c].y * ec[c].y;
            p[c].z = rc[c].z * ec[c].z;
            p[c].w = rc[c].w * ec[c].w;
            ep[c]  = dot4(rc[c], fr) + dot4(ec[c], fe);
        }
        float sit = dot4(itc, fi);
        const float4 it_cur = itc;
        const int adj_cur = adjc, id_cur = idc;

        // ---- issue next node's loads (in flight across both barriers) -----
        int np = n + ST; if (np >= N) np = n0;   // clamp target never consumed
        {
            const float* bR = rel + (size_t)np * 4096;
            const float* bE = ent + (size_t)np * 4096;
            #pragma unroll
            for (int c = 0; c < 4; ++c) {
                const int kk = kb + 2 * c + hi;
                rc[c] = *(const float4*)&bR[kk * 128 + 4 * lh];
                ec[c] = *(const float4*)&bE[kk * 128 + 4 * lh];
            }
            itc  = *(const float4*)&item[(size_t)np * 128 + 4 * lh];
            adjc = adj[(size_t)np * 32 + lh];
            idc  = rel_ids[(size_t)np * 32 + lh];
        }

        // ---- reduce e-partials within each 32-lane half -------------------
        #pragma unroll
        for (int s = 16; s >= 1; s >>= 1) sit += __shfl_xor(sit, s, 32);
        #pragma unroll
        for (int c = 0; c < 4; ++c) {
            float v = ep[c];
            #pragma unroll
            for (int s = 16; s >= 1; s >>= 1) v += __shfl_xor(v, s, 32);
            ep[c] = v;
        }
        #pragma unroll
        for (int c = 0; c < 4; ++c)
            if (lh == c) e_lds[kb + 2 * c + hi] = ep[c];
        block_bar();                                   // barrier 1

        // ---- masked softmax (lane-parallel k=lh, redundant per wave) ------
        float e = e_lds[lh] + sit + fcb;
        e = (e > 0.0f) ? e : ALPHA * e;                // LeakyReLU
        float ex = (adj_cur > 0) ? __expf(e) : 0.0f;   // mask (no max-sub; N(0,1))
        float Z = ex;
        #pragma unroll
        for (int s = 16; s >= 1; s >>= 1) Z += __shfl_xor(Z, s, 32);
        const bool  vld = (id_cur >= 0) && (id_cur < R);
        const float a   = vld ? asum[vld ? id_cur : 0] : 0.0f;
        const float wk  = (Z > 0.0f) ? (ex * a / Z) : (a * (1.0f / 32.0f));

        // ---- partial aggregate over this wave's 8 k's ---------------------
        float4 acc = make_float4(0.f, 0.f, 0.f, 0.f);
        #pragma unroll
        for (int c = 0; c < 4; ++c) {
            const float wc = __shfl(wk, kb + 2 * c + hi, 32);
            acc.x = fmaf(wc, p[c].x, acc.x);
            acc.y = fmaf(wc, p[c].y, acc.y);
            acc.z = fmaf(wc, p[c].z, acc.z);
            acc.w = fmaf(wc, p[c].w, acc.w);
        }
        acc.x += __shfl_xor(acc.x, 32, 64);
        acc.y += __shfl_xor(acc.y, 32, 64);
        acc.z += __shfl_xor(acc.z, 32, 64);
        acc.w += __shfl_xor(acc.w, 32, 64);
        if (hi == 0) *(float4*)&part[w][4 * lh] = acc;
        block_bar();                                   // barrier 2

        // ---- cross-wave sum + residual + store (wave 0, lanes 0..31) ------
        if (t < 32) {
            const float4 a0 = *(const float4*)&part[0][4 * t];
            const float4 a1 = *(const float4*)&part[1][4 * t];
            const float4 a2 = *(const float4*)&part[2][4 * t];
            const float4 a3 = *(const float4*)&part[3][4 * t];
            float4 o;
            o.x = a0.x + a1.x + a2.x + a3.x + it_cur.x;
            o.y = a0.y + a1.y + a2.y + a3.y + it_cur.y;
            o.z = a0.z + a1.z + a2.z + a3.z + it_cur.z;
            o.w = a0.w + a1.w + a2.w + a3.w + it_cur.w;
            *(float4*)&y[(size_t)n * 128 + 4 * t] = o;
        }
    }
}

// K2: out = relu(y @ W^T + b), in place on d_out (unchanged).
__global__ __launch_bounds__(256, 4)
void gat_k2(const float* __restrict__ out_w,
            const float* __restrict__ out_b,
            float* __restrict__ y, int N)
{
    __shared__ __align__(16) float ylds[128];
    __shared__ __align__(16) float plds[1024];   // [4 a][32 g][8 c]

    const int t = threadIdx.x;
    const int c = t & 7;
    const int g = t >> 3;

    float4 w4[16];
    #pragma unroll
    for (int a = 0; a < 4; ++a)
        #pragma unroll
        for (int i = 0; i < 4; ++i)
            w4[a * 4 + i] = *(const float4*)&out_w[(size_t)(g * 4 + a) * 128 + c * 16 + i * 4];
    const float bj = out_b[t & 127];
    const int stride = gridDim.x;

    float vcur = 0.0f;
    if (t < 128) vcur = y[(size_t)blockIdx.x * 128 + t];

    for (int n = blockIdx.x; n < N; n += stride) {
        if (t < 128) ylds[t] = vcur;
        block_bar();
        int np = n + stride; if (np >= N) np = n;
        float vn = 0.0f;
        if (t < 128) vn = y[(size_t)np * 128 + t];

        float4 yc[4];
        #pragma unroll
        for (int i = 0; i < 4; ++i) yc[i] = *(const float4*)&ylds[c * 16 + i * 4];
        #pragma unroll
        for (int a = 0; a < 4; ++a) {
            float s = 0.0f;
            #pragma unroll
            for (int i = 0; i < 4; ++i) s += dot4(w4[a * 4 + i], yc[i]);
            plds[a * 256 + g * 8 + c] = s;
        }
        block_bar();
        if (t < 128) {
            const int j = t, a2 = j & 3, g2 = j >> 2;
            const float* pp = &plds[a2 * 256 + g2 * 8];
            float4 u0 = *(const float4*)pp;
            float4 u1 = *(const float4*)(pp + 4);
            float s = u0.x + u0.y + u0.z + u0.w + u1.x + u1.y + u1.z + u1.w + bj;
            y[(size_t)n * 128 + j] = fmaxf(s, 0.0f);
        }
        vcur = vn;
    }
}

extern "C" void kernel_launch(void* const* d_in, const int* in_sizes, int n_in,
                              void* d_out, int out_size, void* d_ws, size_t ws_size,
                              hipStream_t stream) {
    const float* item    = (const float*)d_in[0];
    const float* ent     = (const float*)d_in[1];
    const float* rel     = (const float*)d_in[2];
    const int*   rel_ids = (const int*)  d_in[3];
    const int*   adj     = (const int*)  d_in[4];
    const float* fc_w    = (const float*)d_in[5];
    const float* fc_b    = (const float*)d_in[6];
    const float* out_w   = (const float*)d_in[7];
    const float* out_b   = (const float*)d_in[8];
    const float* probs   = (const float*)d_in[9];
    float* out = (float*)d_out;

    const int N = in_sizes[0] / 128;   // 20000
    const int R = in_sizes[9] / 4;     // 100

    // 2000 blocks x 1 node each iteration: exactly 10 iterations per block.
    hipLaunchKernelGGL(gat_k1, dim3(2000), dim3(256), 0, stream,
                       item, ent, rel, rel_ids, adj, fc_w, fc_b, probs, out, N, R);

    int blocks2 = 2048; if (blocks2 > N) blocks2 = N;
    hipLaunchKernelGGL(gat_k2, dim3(blocks2), dim3(256), 0, stream,
                       out_w, out_b, out, N);
}

// Round 8
// 140.589 us; speedup vs baseline: 1.1420x; 1.1364x over previous
//
#include <hip/hip_runtime.h>

#define ALPHA 0.2f

__device__ __forceinline__ float dot4(float4 a, float4 b) {
    return a.x * b.x + a.y * b.y + a.z * b.z + a.w * b.w;
}

__device__ __forceinline__ void block_bar() {
    // drain LDS ops only; global loads stay in flight
    asm volatile("s_waitcnt lgkmcnt(0)" ::: "memory");
    __builtin_amdgcn_s_barrier();
}

// Fully fused: attention + aggregation + residual + output GEMV + ReLU.
// 4 waves per node; out_w held in registers (64 VGPR/lane, loaded once/block).
__global__ __launch_bounds__(256, 2)
void gat_fused(const float* __restrict__ item,
               const float* __restrict__ ent,
               const float* __restrict__ rel,
               const int*   __restrict__ rel_ids,
               const int*   __restrict__ adj,
               const float* __restrict__ fc_w,
               const float* __restrict__ fc_b,
               const float* __restrict__ out_w,
               const float* __restrict__ out_b,
               const float* __restrict__ probs,
               float* __restrict__ out,
               int N, int R)
{
    __shared__ float e_lds[32];
    __shared__ __align__(16) float part[4][128];
    __shared__ __align__(16) float ylds[128];
    __shared__ float asum[128];

    const int t  = threadIdx.x;
    const int w  = t >> 6;       // wave 0..3
    const int l  = t & 63;
    const int lh = l & 31;       // d-quad index (data), k index (softmax), j-in-wave (gemv)
    const int hi = l >> 5;       // half index
    const int kb = w * 8;        // this wave's k-range [kb, kb+8)

    for (int i = t; i < R; i += 256) {
        float4 q = *(const float4*)&probs[i * 4];
        asum[i] = q.x + q.y + q.z + q.w;
    }
    const float4 fi = *(const float4*)&fc_w[4 * lh];
    const float4 fr = *(const float4*)&fc_w[128 + 4 * lh];
    const float4 fe = *(const float4*)&fc_w[256 + 4 * lh];
    const float fcb = fc_b[0];

    // out_w rows for this wave: j = w*32 + lh, d-half = hi. 64 VGPRs, once per block.
    const int j = w * 32 + lh;
    float4 w64[16];
    {
        const float* wrow = out_w + (size_t)j * 128 + hi * 64;
        #pragma unroll
        for (int i = 0; i < 16; ++i) w64[i] = *(const float4*)&wrow[4 * i];
    }
    const float bj = out_b[j];
    __syncthreads();

    const int ST = gridDim.x;
    const int n0 = blockIdx.x;

    // prologue: load node n0
    float4 rc[4], ec[4], itc;
    int adjc, idc;
    {
        const float* bR = rel + (size_t)n0 * 4096;
        const float* bE = ent + (size_t)n0 * 4096;
        #pragma unroll
        for (int c = 0; c < 4; ++c) {
            const int kk = kb + 2 * c + hi;
            rc[c] = *(const float4*)&bR[kk * 128 + 4 * lh];
            ec[c] = *(const float4*)&bE[kk * 128 + 4 * lh];
        }
        itc  = *(const float4*)&item[(size_t)n0 * 128 + 4 * lh];
        adjc = adj[(size_t)n0 * 32 + lh];
        idc  = rel_ids[(size_t)n0 * 32 + lh];
    }

    for (int n = n0; n < N; n += ST) {
        // ---- consume current regs: products + e-partials ------------------
        float4 p[4];
        float  ep[4];
        #pragma unroll
        for (int c = 0; c < 4; ++c) {
            p[c].x = rc[c].x * ec[c].x;
            p[c].y = rc[c].y * ec[c].y;
            p[c].z = rc[c].z * ec[c].z;
            p[c].w = rc[c].w * ec[c].w;
            ep[c]  = dot4(rc[c], fr) + dot4(ec[c], fe);
        }
        float sit = dot4(itc, fi);
        const float4 it_cur = itc;
        const int adj_cur = adjc, id_cur = idc;

        // ---- issue next node's loads ---------------------------------------
        int np = n + ST; if (np >= N) np = n0;   // clamp target never consumed
        {
            const float* bR = rel + (size_t)np * 4096;
            const float* bE = ent + (size_t)np * 4096;
            #pragma unroll
            for (int c = 0; c < 4; ++c) {
                const int kk = kb + 2 * c + hi;
                rc[c] = *(const float4*)&bR[kk * 128 + 4 * lh];
                ec[c] = *(const float4*)&bE[kk * 128 + 4 * lh];
            }
            itc  = *(const float4*)&item[(size_t)np * 128 + 4 * lh];
            adjc = adj[(size_t)np * 32 + lh];
            idc  = rel_ids[(size_t)np * 32 + lh];
        }

        // ---- reduce e-partials within each 32-lane half -------------------
        #pragma unroll
        for (int s = 16; s >= 1; s >>= 1) sit += __shfl_xor(sit, s, 32);
        #pragma unroll
        for (int c = 0; c < 4; ++c) {
            float v = ep[c];
            #pragma unroll
            for (int s = 16; s >= 1; s >>= 1) v += __shfl_xor(v, s, 32);
            ep[c] = v;
        }
        #pragma unroll
        for (int c = 0; c < 4; ++c)
            if (lh == c) e_lds[kb + 2 * c + hi] = ep[c];
        block_bar();                                   // barrier 1

        // ---- masked softmax (lane-parallel k=lh, redundant per wave) ------
        float e = e_lds[lh] + sit + fcb;
        e = (e > 0.0f) ? e : ALPHA * e;                // LeakyReLU
        float ex = (adj_cur > 0) ? __expf(e) : 0.0f;   // mask (no max-sub; N(0,1))
        float Z = ex;
        #pragma unroll
        for (int s = 16; s >= 1; s >>= 1) Z += __shfl_xor(Z, s, 32);
        const bool  vld = (id_cur >= 0) && (id_cur < R);
        const float a   = vld ? asum[id_cur] : 0.0f;
        const float wk  = (Z > 0.0f) ? (ex * a / Z) : (a * (1.0f / 32.0f));

        // ---- partial aggregate over this wave's 8 k's ---------------------
        float4 acc = make_float4(0.f, 0.f, 0.f, 0.f);
        #pragma unroll
        for (int c = 0; c < 4; ++c) {
            const float wc = __shfl(wk, kb + 2 * c + hi, 32);
            acc.x = fmaf(wc, p[c].x, acc.x);
            acc.y = fmaf(wc, p[c].y, acc.y);
            acc.z = fmaf(wc, p[c].z, acc.z);
            acc.w = fmaf(wc, p[c].w, acc.w);
        }
        acc.x += __shfl_xor(acc.x, 32, 64);
        acc.y += __shfl_xor(acc.y, 32, 64);
        acc.z += __shfl_xor(acc.z, 32, 64);
        acc.w += __shfl_xor(acc.w, 32, 64);
        if (hi == 0) *(float4*)&part[w][4 * lh] = acc;
        block_bar();                                   // barrier 2

        // ---- final y -> LDS (wave 0, lanes 0..31) -------------------------
        if (t < 32) {
            const float4 a0 = *(const float4*)&part[0][4 * t];
            const float4 a1 = *(const float4*)&part[1][4 * t];
            const float4 a2 = *(const float4*)&part[2][4 * t];
            const float4 a3 = *(const float4*)&part[3][4 * t];
            float4 o;
            o.x = a0.x + a1.x + a2.x + a3.x + it_cur.x;
            o.y = a0.y + a1.y + a2.y + a3.y + it_cur.y;
            o.z = a0.z + a1.z + a2.z + a3.z + it_cur.z;
            o.w = a0.w + a1.w + a2.w + a3.w + it_cur.w;
            *(float4*)&ylds[4 * t] = o;
        }
        block_bar();                                   // barrier 3

        // ---- output GEMV: wave w -> rows [w*32, w*32+32), halves over hi --
        float s = 0.0f;
        #pragma unroll
        for (int i = 0; i < 16; ++i) {
            const float4 yv = *(const float4*)&ylds[hi * 64 + 4 * i];  // broadcast
            s += dot4(w64[i], yv);
        }
        s += __shfl_xor(s, 32, 64);                    // merge d-halves
        if (hi == 0)
            out[(size_t)n * 128 + j] = fmaxf(s + bj, 0.0f);
    }
}

extern "C" void kernel_launch(void* const* d_in, const int* in_sizes, int n_in,
                              void* d_out, int out_size, void* d_ws, size_t ws_size,
                              hipStream_t stream) {
    const float* item    = (const float*)d_in[0];
    const float* ent     = (const float*)d_in[1];
    const float* rel     = (const float*)d_in[2];
    const int*   rel_ids = (const int*)  d_in[3];
    const int*   adj     = (const int*)  d_in[4];
    const float* fc_w    = (const float*)d_in[5];
    const float* fc_b    = (const float*)d_in[6];
    const float* out_w   = (const float*)d_in[7];
    const float* out_b   = (const float*)d_in[8];
    const float* probs   = (const float*)d_in[9];
    float* out = (float*)d_out;

    const int N = in_sizes[0] / 128;   // 20000
    const int R = in_sizes[9] / 4;     // 100

    // 512 persistent blocks (<= resident capacity at 2 blocks/CU), ~39 nodes each.
    hipLaunchKernelGGL(gat_fused, dim3(512), dim3(256), 0, stream,
                       item, ent, rel, rel_ids, adj, fc_w, fc_b,
                       out_w, out_b, probs, out, N, R);
}